// Round 1
// baseline (3333.717 us; speedup 1.0000x reference)
//
#include <hip/hip_runtime.h>
#include <math.h>

#define NB 20000
#define SPIN 365
#define TRAINLEN 15000
#define ML_C 2.9086f
#define SL_C 1.898f

#if defined(__has_builtin)
#if __has_builtin(__builtin_amdgcn_exp2f)
#define EX2(x) __builtin_amdgcn_exp2f(x)
#else
#define EX2(x) exp2f(x)
#endif
#else
#define EX2(x) exp2f(x)
#endif
#define RCP(x) __builtin_amdgcn_rcpf(x)

struct Params {
  float oo1, oogw1, oofp1, ol1, expC;
  float k_oo, d_oo, k_gw, d_gw, k_fp, d_fp, k_ol, d_ol;
};

struct StepOut {
  float h, hfp, l, lc, bp, gw, ib, oo, oofp, ol, olc, f, oogw, c1;
};

__device__ __forceinline__ StepOut do_step(float c0, float u1, float u2, const Params& P) {
  StepOut o;
  // bypass / overflow flux
  float px = fmaxf(u1 + c0 - P.expC, 0.f);
  float ib = (u1 > 0.f) ? px * RCP(u1) : 0.f;
  // sigmoid(b + z*w) with constants folded: exp(-arg) = exp2(c0*k + d)
  float soo = RCP(1.f + EX2(fmaf(c0, P.k_oo, P.d_oo)));
  float sgw = RCP(1.f + EX2(fmaf(c0, P.k_gw, P.d_gw)));
  float sfp = RCP(1.f + EX2(fmaf(c0, P.k_fp, P.d_fp)));
  float sol = RCP(1.f + EX2(fmaf(u2, P.k_ol, P.d_ol)));
  float oo = P.oo1 * soo;
  float oogw = P.oogw1 * sgw;
  float oofp = P.oofp1 * sfp;
  float ol = P.ol1 * sol;
  // olc = c0>0 ? ol - relu(ol - u2/c0) : ol   (select, not arithmetic mask, to dodge 0*inf NaN)
  float ratio = u2 * RCP(c0);
  float olc2 = ol - fmaxf(ol - ratio, 0.f);
  float olc = (c0 > 0.f) ? olc2 : ol;
  float fg = 1.f - oo - oofp - oogw - olc;
  o.h = fmaf(oo, c0, px);
  o.hfp = oofp * c0;
  o.l = ol * c0;
  o.lc = olc * c0;
  o.bp = px;
  o.gw = oogw * c0;
  o.ib = ib;
  o.oo = oo; o.oofp = oofp; o.ol = ol; o.olc = olc; o.f = fg; o.oogw = oogw;
  o.c1 = fmaf(fg, c0, u1 - px);
  return o;
}

// obsstd = std(y_obs[SPIN:TRAINLEN], ddof=1), double accumulation
__global__ __launch_bounds__(256) void std_kernel(const float* __restrict__ y,
                                                  float* __restrict__ ws) {
  __shared__ double sh1[256];
  __shared__ double sh2[256];
  int t = threadIdx.x;
  double a = 0.0, q = 0.0;
  for (int i = SPIN + t; i < TRAINLEN; i += 256) {
    double v = (double)y[i];
    a += v;
    q += v * v;
  }
  sh1[t] = a; sh2[t] = q;
  __syncthreads();
  for (int s = 128; s > 0; s >>= 1) {
    if (t < s) { sh1[t] += sh1[t + s]; sh2[t] += sh2[t + s]; }
    __syncthreads();
  }
  if (t == 0) {
    double n = (double)(TRAINLEN - SPIN);
    double var = (sh2[0] - sh1[0] * sh1[0] / n) / (n - 1.0);
    ws[0] = (float)sqrt(var);
  }
}

__global__ __launch_bounds__(256, 1) void scan_kernel(
    const float* __restrict__ x,
    const float* __restrict__ p_mean, const float* __restrict__ p_std,
    const int* __restrict__ time_lag,
    const float* __restrict__ w_r_yom, const float* __restrict__ w_r_yom_fp,
    const float* __restrict__ w_r_yom_gw, const float* __restrict__ w_r_ylm,
    const float* __restrict__ w_r_yfm,
    const float* __restrict__ w_b1_yom, const float* __restrict__ w_b1_yom_gw,
    const float* __restrict__ w_b1_yom_fp, const float* __restrict__ w_b2_ylm,
    const float* __restrict__ theltaC,
    const float* __restrict__ b0_yom, const float* __restrict__ b0_yom_gw,
    const float* __restrict__ b0_yom_fp, const float* __restrict__ b0_ylm,
    float* __restrict__ out, float* __restrict__ ws) {
  const int tid = threadIdx.x;
  if (tid >= 64) {
    // waves 1-3: warm this XCD's L2 with x so the serial lane hits L2 (~200cy) not HBM (~900cy)
    float s = 0.f;
    for (int i = tid - 64; i < 2 * NB; i += 192) s += x[i];
    if (s == -1.2345e37f) ws[1] = s;  // never true; keeps the loads alive
    return;
  }
  if (tid != 0) return;  // lane 0 of wave 0 runs the scan

  // ---- fold all parameters into per-step constants ----
  float e1 = __expf(w_r_yom[0]);
  float e2 = __expf(w_r_yom_gw[0]);
  float e3 = __expf(w_r_ylm[0]);
  float e4 = __expf(w_r_yfm[0]);
  float e5 = __expf(w_r_yom_fp[0]);
  float rd = 1.f / (e1 + e2 + e3 + e4 + e5);
  Params P;
  P.oo1 = e1 * rd;
  P.oogw1 = e2 * rd;
  P.ol1 = e3 * rd;
  P.oofp1 = e5 * rd;
  P.expC = __expf(theltaC[0]);
  const float L2E = 1.4426950408889634f;
  float mo = p_mean[0];
  float inv_so = 1.f / p_std[0];
  float w1 = w_b1_yom[0], w1gw = w_b1_yom_gw[0], w1fp = w_b1_yom_fp[0], w2 = w_b2_ylm[0];
  P.k_oo = -L2E * (w1 * inv_so);
  P.d_oo = -L2E * (b0_yom[0] - mo * inv_so * w1);
  P.k_gw = -L2E * (w1gw * inv_so);
  P.d_gw = -L2E * (b0_yom_gw[0] - mo * inv_so * w1gw);
  P.k_fp = -L2E * (w1fp * inv_so);
  P.d_fp = -L2E * (b0_yom_fp[0] - mo * inv_so * w1fp);
  P.k_ol = -L2E * (w2 / SL_C);
  P.d_ol = -L2E * (b0_ylm[0] - (ML_C / SL_C) * w2);
  const int tl = time_lag[0];

  float* o_h    = out;
  float* o_hfp  = out + NB;
  float* o_c    = out + 2 * NB;
  float* o_l    = out + 3 * NB;
  float* o_lc   = out + 4 * NB;
  float* o_bp   = out + 5 * NB;
  float* o_gw   = out + 6 * NB;
  float* o_ib   = out + 7 * NB;
  float* o_oo   = out + 8 * NB;
  float* o_oofp = out + 9 * NB;
  float* o_ol   = out + 10 * NB;
  float* o_olc  = out + 11 * NB;
  float* o_f    = out + 12 * NB;
  float* o_oogw = out + 13 * NB;

  const float2* __restrict__ xv = (const float2*)x;
  float2 cur[8], nxt[8];
#pragma unroll
  for (int i = 0; i < 8; ++i) cur[i] = xv[i];
  float c0 = 0.f;

  for (int base = 0; base < NB; base += 8) {
    // prefetch next chunk (independent of the serial chain; waits land on the
    // cur=nxt copies at the bottom, ~8 steps (~450cy) later)
#pragma unroll
    for (int i = 0; i < 8; ++i) {
      int j = base + 8 + i;
      nxt[i] = xv[j < NB ? j : 0];
    }
    float vh[8], vhfp[8], vc[8], vl[8], vlc[8], vbp[8], vgw[8], vib[8];
    float voo[8], voofp[8], vol[8], volc[8], vf[8], voogw[8];
    if (base >= tl) {  // fast path: all 8 steps active (always taken when time_lag==0)
#pragma unroll
      for (int i = 0; i < 8; ++i) {
        StepOut s = do_step(c0, cur[i].x, cur[i].y, P);
        vh[i] = s.h; vhfp[i] = s.hfp; vc[i] = c0; vl[i] = s.l; vlc[i] = s.lc;
        vbp[i] = s.bp; vgw[i] = s.gw; vib[i] = s.ib; voo[i] = s.oo;
        voofp[i] = s.oofp; vol[i] = s.ol; volc[i] = s.olc; vf[i] = s.f;
        voogw[i] = s.oogw;
        c0 = s.c1;
      }
    } else {  // general path: per-step active mask
#pragma unroll
      for (int i = 0; i < 8; ++i) {
        StepOut s = do_step(c0, cur[i].x, cur[i].y, P);
        bool act = (base + i) >= tl;
        float m = act ? 1.f : 0.f;
        vh[i] = m * s.h; vhfp[i] = m * s.hfp; vc[i] = m * c0; vl[i] = m * s.l;
        vlc[i] = m * s.lc; vbp[i] = m * s.bp; vgw[i] = m * s.gw; vib[i] = m * s.ib;
        voo[i] = m * s.oo; voofp[i] = m * s.oofp; vol[i] = m * s.ol;
        volc[i] = m * s.olc; vf[i] = m * s.f; voogw[i] = m * s.oogw;
        c0 = act ? s.c1 : c0;
      }
    }
    // flush as dwordx4: 28 stores per 8 steps instead of 112 scalar stores
#pragma unroll
    for (int g = 0; g < 2; ++g) {
      int o = base + 4 * g;
      int q = 4 * g;
      *(float4*)(o_h + o)    = make_float4(vh[q], vh[q+1], vh[q+2], vh[q+3]);
      *(float4*)(o_hfp + o)  = make_float4(vhfp[q], vhfp[q+1], vhfp[q+2], vhfp[q+3]);
      *(float4*)(o_c + o)    = make_float4(vc[q], vc[q+1], vc[q+2], vc[q+3]);
      *(float4*)(o_l + o)    = make_float4(vl[q], vl[q+1], vl[q+2], vl[q+3]);
      *(float4*)(o_lc + o)   = make_float4(vlc[q], vlc[q+1], vlc[q+2], vlc[q+3]);
      *(float4*)(o_bp + o)   = make_float4(vbp[q], vbp[q+1], vbp[q+2], vbp[q+3]);
      *(float4*)(o_gw + o)   = make_float4(vgw[q], vgw[q+1], vgw[q+2], vgw[q+3]);
      *(float4*)(o_ib + o)   = make_float4(vib[q], vib[q+1], vib[q+2], vib[q+3]);
      *(float4*)(o_oo + o)   = make_float4(voo[q], voo[q+1], voo[q+2], voo[q+3]);
      *(float4*)(o_oofp + o) = make_float4(voofp[q], voofp[q+1], voofp[q+2], voofp[q+3]);
      *(float4*)(o_ol + o)   = make_float4(vol[q], vol[q+1], vol[q+2], vol[q+3]);
      *(float4*)(o_olc + o)  = make_float4(volc[q], volc[q+1], volc[q+2], volc[q+3]);
      *(float4*)(o_f + o)    = make_float4(vf[q], vf[q+1], vf[q+2], vf[q+3]);
      *(float4*)(o_oogw + o) = make_float4(voogw[q], voogw[q+1], voogw[q+2], voogw[q+3]);
    }
#pragma unroll
    for (int i = 0; i < 8; ++i) cur[i] = nxt[i];
  }
}

// obs_std column + h_nout interleave (reads already-written h)
__global__ __launch_bounds__(256) void fill_kernel(const float* __restrict__ ws,
                                                   const int* __restrict__ tlp,
                                                   float* __restrict__ out) {
  int b = blockIdx.x * 256 + threadIdx.x;
  if (b >= NB) return;
  float v = (b >= tlp[0]) ? ws[0] : 0.f;
  float h = out[b];
  float2* hn = (float2*)(out + 14 * NB);
  hn[b] = make_float2(h, v);
  out[16 * NB + b] = v;
}

extern "C" void kernel_launch(void* const* d_in, const int* in_sizes, int n_in,
                              void* d_out, int out_size, void* d_ws, size_t ws_size,
                              hipStream_t stream) {
  const float* x        = (const float*)d_in[0];
  const float* y_obs    = (const float*)d_in[1];
  const float* p_mean   = (const float*)d_in[2];
  const float* p_std    = (const float*)d_in[3];
  // d_in[4] = epoch (unused by reference)
  const int* time_lag   = (const int*)d_in[5];
  const float* w_r_yom    = (const float*)d_in[6];
  const float* w_r_yom_fp = (const float*)d_in[7];
  const float* w_r_yom_gw = (const float*)d_in[8];
  const float* w_r_ylm    = (const float*)d_in[9];
  const float* w_r_yfm    = (const float*)d_in[10];
  const float* w_b1_yom   = (const float*)d_in[11];
  const float* w_b1_yom_gw= (const float*)d_in[12];
  const float* w_b1_yom_fp= (const float*)d_in[13];
  const float* w_b2_ylm   = (const float*)d_in[14];
  const float* theltaC    = (const float*)d_in[15];
  const float* b0_yom     = (const float*)d_in[16];
  const float* b0_yom_gw  = (const float*)d_in[17];
  const float* b0_yom_fp  = (const float*)d_in[18];
  const float* b0_ylm     = (const float*)d_in[19];
  float* out = (float*)d_out;
  float* ws = (float*)d_ws;

  std_kernel<<<1, 256, 0, stream>>>(y_obs, ws);
  scan_kernel<<<1, 256, 0, stream>>>(x, p_mean, p_std, time_lag,
                                     w_r_yom, w_r_yom_fp, w_r_yom_gw, w_r_ylm, w_r_yfm,
                                     w_b1_yom, w_b1_yom_gw, w_b1_yom_fp, w_b2_ylm,
                                     theltaC, b0_yom, b0_yom_gw, b0_yom_fp, b0_ylm,
                                     out, ws);
  fill_kernel<<<(NB + 255) / 256, 256, 0, stream>>>(ws, time_lag, out);
}

// Round 2
// 123.371 us; speedup vs baseline: 27.0219x; 27.0219x over previous
//
#include <hip/hip_runtime.h>
#include <math.h>

#define NB 20000
#define SPIN 365
#define TRAINLEN 15000
#define ML_C 2.9086f
#define SL_C 1.898f

// speculative decoupling: each lane owns CHUNK steps, warm-up WSPEC steps
// from a speculated c=0 (recurrence is a contraction, f in (0,1), ~0.6 typ:
// 0.9^128 ~ 1.4e-6 even pessimistically -> far under the 2.45e-2 threshold)
#define CHUNK 10
#define WSPEC 128
#define LANES_PER_BLOCK 64

#if defined(__has_builtin)
#if __has_builtin(__builtin_amdgcn_exp2f)
#define EX2(x) __builtin_amdgcn_exp2f(x)
#else
#define EX2(x) exp2f(x)
#endif
#else
#define EX2(x) exp2f(x)
#endif
#define RCP(x) __builtin_amdgcn_rcpf(x)

struct Params {
  float oo1, oogw1, oofp1, ol1, expC;
  float k_oo, d_oo, k_gw, d_gw, k_fp, d_fp, k_ol, d_ol;
};

struct StepOut {
  float h, hfp, l, lc, bp, gw, ib, oo, oofp, ol, olc, f, oogw, c1;
};

__device__ __forceinline__ StepOut do_step(float c0, float u1, float u2, const Params& P) {
  StepOut o;
  float px = fmaxf(u1 + c0 - P.expC, 0.f);
  float ib = (u1 > 0.f) ? px * RCP(u1) : 0.f;
  float soo = RCP(1.f + EX2(fmaf(c0, P.k_oo, P.d_oo)));
  float sgw = RCP(1.f + EX2(fmaf(c0, P.k_gw, P.d_gw)));
  float sfp = RCP(1.f + EX2(fmaf(c0, P.k_fp, P.d_fp)));
  float sol = RCP(1.f + EX2(fmaf(u2, P.k_ol, P.d_ol)));
  float oo = P.oo1 * soo;
  float oogw = P.oogw1 * sgw;
  float oofp = P.oofp1 * sfp;
  float ol = P.ol1 * sol;
  float ratio = u2 * RCP(c0);
  float olc2 = ol - fmaxf(ol - ratio, 0.f);
  float olc = (c0 > 0.f) ? olc2 : ol;
  float fg = 1.f - oo - oofp - oogw - olc;
  o.h = fmaf(oo, c0, px);
  o.hfp = oofp * c0;
  o.l = ol * c0;
  o.lc = olc * c0;
  o.bp = px;
  o.gw = oogw * c0;
  o.ib = ib;
  o.oo = oo; o.oofp = oofp; o.ol = ol; o.olc = olc; o.f = fg; o.oogw = oogw;
  o.c1 = fmaf(fg, c0, u1 - px);
  return o;
}

// obsstd = std(y_obs[SPIN:TRAINLEN], ddof=1), double accumulation
__global__ __launch_bounds__(1024) void std_kernel(const float* __restrict__ y,
                                                   float* __restrict__ ws) {
  __shared__ double sh1[1024];
  __shared__ double sh2[1024];
  int t = threadIdx.x;
  double a = 0.0, q = 0.0;
  for (int i = SPIN + t; i < TRAINLEN; i += 1024) {
    double v = (double)y[i];
    a += v;
    q += v * v;
  }
  sh1[t] = a; sh2[t] = q;
  __syncthreads();
  for (int s = 512; s > 0; s >>= 1) {
    if (t < s) { sh1[t] += sh1[t + s]; sh2[t] += sh2[t + s]; }
    __syncthreads();
  }
  if (t == 0) {
    double n = (double)(TRAINLEN - SPIN);
    double var = (sh2[0] - sh1[0] * sh1[0] / n) / (n - 1.0);
    ws[0] = (float)sqrt(var);
  }
}

__global__ __launch_bounds__(LANES_PER_BLOCK) void scan_spec_kernel(
    const float* __restrict__ x,
    const float* __restrict__ p_mean, const float* __restrict__ p_std,
    const int* __restrict__ time_lag,
    const float* __restrict__ w_r_yom, const float* __restrict__ w_r_yom_fp,
    const float* __restrict__ w_r_yom_gw, const float* __restrict__ w_r_ylm,
    const float* __restrict__ w_r_yfm,
    const float* __restrict__ w_b1_yom, const float* __restrict__ w_b1_yom_gw,
    const float* __restrict__ w_b1_yom_fp, const float* __restrict__ w_b2_ylm,
    const float* __restrict__ theltaC,
    const float* __restrict__ b0_yom, const float* __restrict__ b0_yom_gw,
    const float* __restrict__ b0_yom_fp, const float* __restrict__ b0_ylm,
    float* __restrict__ out, const float* __restrict__ ws) {
  const int gid = blockIdx.x * LANES_PER_BLOCK + threadIdx.x;
  const int start = gid * CHUNK;
  if (start >= NB) return;

  // fold all parameters into per-step constants (tiny, done by every lane)
  float e1 = __expf(w_r_yom[0]);
  float e2 = __expf(w_r_yom_gw[0]);
  float e3 = __expf(w_r_ylm[0]);
  float e4 = __expf(w_r_yfm[0]);
  float e5 = __expf(w_r_yom_fp[0]);
  float rd = 1.f / (e1 + e2 + e3 + e4 + e5);
  Params P;
  P.oo1 = e1 * rd;
  P.oogw1 = e2 * rd;
  P.ol1 = e3 * rd;
  P.oofp1 = e5 * rd;
  P.expC = __expf(theltaC[0]);
  const float L2E = 1.4426950408889634f;
  float mo = p_mean[0];
  float inv_so = 1.f / p_std[0];
  float w1 = w_b1_yom[0], w1gw = w_b1_yom_gw[0], w1fp = w_b1_yom_fp[0], w2 = w_b2_ylm[0];
  P.k_oo = -L2E * (w1 * inv_so);
  P.d_oo = -L2E * (b0_yom[0] - mo * inv_so * w1);
  P.k_gw = -L2E * (w1gw * inv_so);
  P.d_gw = -L2E * (b0_yom_gw[0] - mo * inv_so * w1gw);
  P.k_fp = -L2E * (w1fp * inv_so);
  P.d_fp = -L2E * (b0_yom_fp[0] - mo * inv_so * w1fp);
  P.k_ol = -L2E * (w2 / SL_C);
  P.d_ol = -L2E * (b0_ylm[0] - (ML_C / SL_C) * w2);
  const int tl = time_lag[0];
  const float sd = ws[0];  // std_kernel completed earlier on this stream

  float* o_h    = out;
  float* o_hfp  = out + NB;
  float* o_c    = out + 2 * NB;
  float* o_l    = out + 3 * NB;
  float* o_lc   = out + 4 * NB;
  float* o_bp   = out + 5 * NB;
  float* o_gw   = out + 6 * NB;
  float* o_ib   = out + 7 * NB;
  float* o_oo   = out + 8 * NB;
  float* o_oofp = out + 9 * NB;
  float* o_ol   = out + 10 * NB;
  float* o_olc  = out + 11 * NB;
  float* o_f    = out + 12 * NB;
  float* o_oogw = out + 13 * NB;
  float2* o_hn  = (float2*)(out + 14 * NB);
  float* o_std  = out + 16 * NB;

  const float2* __restrict__ xv = (const float2*)x;
  const int begin = start - WSPEC;

  // distance-4 register ring prefetch (clamped addresses for idx<0 lanes)
  float2 xbuf[4];
#pragma unroll
  for (int k = 0; k < 4; ++k) {
    int j = begin + k;
    j = j < 0 ? 0 : (j >= NB ? NB - 1 : j);
    xbuf[k] = xv[j];
  }

  float c = 0.f;
  const int T = WSPEC + CHUNK;
  for (int t = 0; t < T; ++t) {
    const int idx = begin + t;
    int jp = idx + 4;
    jp = jp < 0 ? 0 : (jp >= NB ? NB - 1 : jp);
    float2 xn = xv[jp];
    float2 xc = xbuf[0];
    xbuf[0] = xbuf[1]; xbuf[1] = xbuf[2]; xbuf[2] = xbuf[3]; xbuf[3] = xn;

    if (idx >= 0) {
      StepOut s = do_step(c, xc.x, xc.y, P);
      bool act = idx >= tl;
      if (t >= WSPEC && idx < NB) {   // t>=WSPEC is wave-uniform
        float m = act ? 1.f : 0.f;
        o_h[idx]    = m * s.h;
        o_hfp[idx]  = m * s.hfp;
        o_c[idx]    = m * c;        // c0 (state entering this step)
        o_l[idx]    = m * s.l;
        o_lc[idx]   = m * s.lc;
        o_bp[idx]   = m * s.bp;
        o_gw[idx]   = m * s.gw;
        o_ib[idx]   = m * s.ib;
        o_oo[idx]   = m * s.oo;
        o_oofp[idx] = m * s.oofp;
        o_ol[idx]   = m * s.ol;
        o_olc[idx]  = m * s.olc;
        o_f[idx]    = m * s.f;
        o_oogw[idx] = m * s.oogw;
        float sv = act ? sd : 0.f;
        o_hn[idx] = make_float2(m * s.h, sv);
        o_std[idx] = sv;
      }
      if (act) c = s.c1;
    }
  }
}

extern "C" void kernel_launch(void* const* d_in, const int* in_sizes, int n_in,
                              void* d_out, int out_size, void* d_ws, size_t ws_size,
                              hipStream_t stream) {
  const float* x        = (const float*)d_in[0];
  const float* y_obs    = (const float*)d_in[1];
  const float* p_mean   = (const float*)d_in[2];
  const float* p_std    = (const float*)d_in[3];
  // d_in[4] = epoch (unused by reference)
  const int* time_lag   = (const int*)d_in[5];
  const float* w_r_yom    = (const float*)d_in[6];
  const float* w_r_yom_fp = (const float*)d_in[7];
  const float* w_r_yom_gw = (const float*)d_in[8];
  const float* w_r_ylm    = (const float*)d_in[9];
  const float* w_r_yfm    = (const float*)d_in[10];
  const float* w_b1_yom   = (const float*)d_in[11];
  const float* w_b1_yom_gw= (const float*)d_in[12];
  const float* w_b1_yom_fp= (const float*)d_in[13];
  const float* w_b2_ylm   = (const float*)d_in[14];
  const float* theltaC    = (const float*)d_in[15];
  const float* b0_yom     = (const float*)d_in[16];
  const float* b0_yom_gw  = (const float*)d_in[17];
  const float* b0_yom_fp  = (const float*)d_in[18];
  const float* b0_ylm     = (const float*)d_in[19];
  float* out = (float*)d_out;
  float* ws = (float*)d_ws;

  std_kernel<<<1, 1024, 0, stream>>>(y_obs, ws);
  const int nlanes = (NB + CHUNK - 1) / CHUNK;
  const int nblocks = (nlanes + LANES_PER_BLOCK - 1) / LANES_PER_BLOCK;
  scan_spec_kernel<<<nblocks, LANES_PER_BLOCK, 0, stream>>>(
      x, p_mean, p_std, time_lag,
      w_r_yom, w_r_yom_fp, w_r_yom_gw, w_r_ylm, w_r_yfm,
      w_b1_yom, w_b1_yom_gw, w_b1_yom_fp, w_b2_ylm,
      theltaC, b0_yom, b0_yom_gw, b0_yom_fp, b0_ylm,
      out, ws);
}

// Round 3
// 121.808 us; speedup vs baseline: 27.3687x; 1.0128x over previous
//
#include <hip/hip_runtime.h>
#include <math.h>

#define NB 20000
#define SPIN 365
#define TRAINLEN 15000
#define ML_C 2.9086f
#define SL_C 1.898f

// speculative decoupling: each lane owns CHUNK steps, warming up WSPEC steps
// from speculated c=0. Measured decay: absmax 9.77e-4 @ W=128 -> f_eff~0.947,
// predicted ~5.6e-3 @ W=96, threshold 2.45e-2.
#define CHUNK 8
#define WSPEC 96
#define TSTEPS (WSPEC + CHUNK)   // 104, multiple of 4
#define LANES_PER_BLOCK 64
#define TPB 512                  // t covered per block = 64 lanes * CHUNK

#if defined(__has_builtin)
#if __has_builtin(__builtin_amdgcn_exp2f)
#define EX2(x) __builtin_amdgcn_exp2f(x)
#else
#define EX2(x) exp2f(x)
#endif
#else
#define EX2(x) exp2f(x)
#endif
#define RCP(x) __builtin_amdgcn_rcpf(x)

#define L2E 1.4426950408889634f

// ------------------------------------------------------------------
// prep: blocks 0..19 build packed[t] = {u1, u2, ol_t, inv_u1} and write the
// o_ol output column; block 20 computes obsstd -> ws[0].
// ------------------------------------------------------------------
__global__ __launch_bounds__(256) void prep_kernel(
    const float* __restrict__ x, const float* __restrict__ y,
    const int* __restrict__ time_lag,
    const float* __restrict__ w_r_yom, const float* __restrict__ w_r_yom_fp,
    const float* __restrict__ w_r_yom_gw, const float* __restrict__ w_r_ylm,
    const float* __restrict__ w_r_yfm,
    const float* __restrict__ w_b2_ylm, const float* __restrict__ b0_ylm,
    float* __restrict__ ws, float* __restrict__ out) {
  __shared__ double sh1[256];
  __shared__ double sh2[256];
  const int t0 = threadIdx.x;
  if (blockIdx.x == 20) {
    // obsstd = std(y[SPIN:TRAINLEN], ddof=1), double accumulation
    double a = 0.0, q = 0.0;
    for (int i = SPIN + t0; i < TRAINLEN; i += 256) {
      double v = (double)y[i];
      a += v; q += v * v;
    }
    sh1[t0] = a; sh2[t0] = q;
    __syncthreads();
    for (int s = 128; s > 0; s >>= 1) {
      if (t0 < s) { sh1[t0] += sh1[t0 + s]; sh2[t0] += sh2[t0 + s]; }
      __syncthreads();
    }
    if (t0 == 0) {
      double n = (double)(TRAINLEN - SPIN);
      double var = (sh2[0] - sh1[0] * sh1[0] / n) / (n - 1.0);
      ws[0] = (float)sqrt(var);
    }
    return;
  }
  // fold ol-gate constants (cheap, per thread)
  float e1 = __expf(w_r_yom[0]);
  float e2 = __expf(w_r_yom_gw[0]);
  float e3 = __expf(w_r_ylm[0]);
  float e4 = __expf(w_r_yfm[0]);
  float e5 = __expf(w_r_yom_fp[0]);
  float ol1 = e3 / (e1 + e2 + e3 + e4 + e5);
  float w2 = w_b2_ylm[0];
  float k_ol = -L2E * (w2 / SL_C);
  float d_ol = -L2E * (b0_ylm[0] - (ML_C / SL_C) * w2);
  const int tl = time_lag[0];

  const float2* __restrict__ xv = (const float2*)x;
  float4* __restrict__ pkd = (float4*)(ws + 16);
  int lo = blockIdx.x * 1000;
  int hi = lo + 1000; if (hi > NB) hi = NB;
  for (int t = lo + t0; t < hi; t += 256) {
    float2 u = xv[t];
    float ol = ol1 * RCP(1.f + EX2(fmaf(u.y, k_ol, d_ol)));
    float iu = (u.x > 0.f) ? RCP(u.x) : 0.f;
    pkd[t] = make_float4(u.x, u.y, ol, iu);
    out[10 * NB + t] = (t >= tl) ? ol : 0.f;   // o_ol column, fully precomputable
  }
}

// ------------------------------------------------------------------
// scan: 1 wave/block; lane owns CHUNK steps after WSPEC warm-up.
// Tail outputs staged in LDS (stride-9 pad), flushed coalesced.
// ------------------------------------------------------------------
__global__ __launch_bounds__(LANES_PER_BLOCK) void scan_spec_kernel(
    const float* __restrict__ ws,
    const int* __restrict__ time_lag,
    const float* __restrict__ p_mean, const float* __restrict__ p_std,
    const float* __restrict__ w_r_yom, const float* __restrict__ w_r_yom_fp,
    const float* __restrict__ w_r_yom_gw, const float* __restrict__ w_r_ylm,
    const float* __restrict__ w_r_yfm,
    const float* __restrict__ w_b1_yom, const float* __restrict__ w_b1_yom_gw,
    const float* __restrict__ w_b1_yom_fp,
    const float* __restrict__ theltaC,
    const float* __restrict__ b0_yom, const float* __restrict__ b0_yom_gw,
    const float* __restrict__ b0_yom_fp,
    float* __restrict__ out) {
  const int lane = threadIdx.x;
  const int gid = blockIdx.x * LANES_PER_BLOCK + lane;
  const int start = gid * CHUNK;

  // ---- fold parameters ----
  float e1 = __expf(w_r_yom[0]);
  float e2 = __expf(w_r_yom_gw[0]);
  float e3 = __expf(w_r_ylm[0]);
  float e4 = __expf(w_r_yfm[0]);
  float e5 = __expf(w_r_yom_fp[0]);
  float rd = 1.f / (e1 + e2 + e3 + e4 + e5);
  float oo1 = e1 * rd, oogw1 = e2 * rd, oofp1 = e5 * rd;
  float expC = __expf(theltaC[0]);
  float mo = p_mean[0];
  float inv_so = 1.f / p_std[0];
  float w1 = w_b1_yom[0], w1gw = w_b1_yom_gw[0], w1fp = w_b1_yom_fp[0];
  float k_oo = -L2E * (w1 * inv_so);
  float d_oo = -L2E * (b0_yom[0] - mo * inv_so * w1);
  float k_gw = -L2E * (w1gw * inv_so);
  float d_gw = -L2E * (b0_yom_gw[0] - mo * inv_so * w1gw);
  float k_fp = -L2E * (w1fp * inv_so);
  float d_fp = -L2E * (b0_yom_fp[0] - mo * inv_so * w1fp);
  const int tl = time_lag[0];
  const float sd = ws[0];

  const float4* __restrict__ pk = (const float4*)(ws + 16);
  const int begin = start - WSPEC;

  // distance-4 register ring (index clamped; warm-up reuse is harmless)
  float4 xb[4];
#pragma unroll
  for (int k = 0; k < 4; ++k) {
    int j = begin + k;
    j = j < 0 ? 0 : (j > NB - 1 ? NB - 1 : j);
    xb[k] = pk[j];
  }

  // 13 columns x (64 lanes * 9) floats; stride-9 kills the 8-way bank conflict
  __shared__ float sh[13 * 576];

  float c = 0.f;
  for (int tt = 0; tt < TSTEPS; tt += 4) {
#pragma unroll
    for (int k = 0; k < 4; ++k) {
      const int t = tt + k;
      const int idx = begin + t;
      int jp = idx + 4;
      jp = jp < 0 ? 0 : (jp > NB - 1 ? NB - 1 : jp);
      float4 xc = xb[k];
      xb[k] = pk[jp];
      if (idx >= 0) {   // divergent only in block 0's warm-up
        float u1 = xc.x, u2 = xc.y, ol = xc.z, iu1 = xc.w;
        float px = fmaxf(u1 + c - expC, 0.f);
        float ib = px * iu1;   // iu1==0 when u1==0 -> ib=0, matches ref
        float soo = RCP(1.f + EX2(fmaf(c, k_oo, d_oo)));
        float sgw = RCP(1.f + EX2(fmaf(c, k_gw, d_gw)));
        float sfp = RCP(1.f + EX2(fmaf(c, k_fp, d_fp)));
        float oo = oo1 * soo, oogw = oogw1 * sgw, oofp = oofp1 * sfp;
        float ratio = u2 * RCP(c);
        float olc = (c > 0.f) ? (ol - fmaxf(ol - ratio, 0.f)) : ol;
        float fg = 1.f - oo - oofp - oogw - olc;
        bool act = idx >= tl;
        if (t >= WSPEC) {      // wave-uniform
          float m = act ? 1.f : 0.f;
          int base = lane * 9 + (t - WSPEC);
          sh[0 * 576 + base] = m * fmaf(oo, c, px);   // h
          sh[1 * 576 + base] = m * (oofp * c);        // hfp
          sh[2 * 576 + base] = m * c;                 // c (state entering step)
          sh[3 * 576 + base] = m * (ol * c);          // l
          sh[4 * 576 + base] = m * (olc * c);         // lc
          sh[5 * 576 + base] = m * px;                // bp
          sh[6 * 576 + base] = m * (oogw * c);        // gw
          sh[7 * 576 + base] = m * ib;                // ib
          sh[8 * 576 + base] = m * oo;                // oo
          sh[9 * 576 + base] = m * oofp;              // oofp
          sh[10 * 576 + base] = m * olc;              // olc
          sh[11 * 576 + base] = m * fg;               // f
          sh[12 * 576 + base] = m * oogw;             // oogw
        }
        if (act) c = fmaf(fg, c, u1 - px);
      }
    }
  }
  __syncthreads();   // 1 wave -> compiles to lgkmcnt wait only

  // ---- coalesced flush: element e in [0,512) lives at LDS (e/8)*9 + e%8 ----
  const int t0b = blockIdx.x * TPB;
  const int colmap[13] = {0, 1, 2, 3, 4, 5, 6, 7, 8, 9, 11, 12, 13};
#pragma unroll
  for (int col = 0; col < 13; ++col) {
    const float* sc = sh + col * 576;
    float* oc = out + colmap[col] * NB;
#pragma unroll
    for (int k2 = 0; k2 < 2; ++k2) {
      int e0 = 4 * (lane + 64 * k2);
      int tg = t0b + e0;
      int a = (e0 >> 3) * 9 + (e0 & 7);   // e0%8 in {0,4}: float4 stays in-row
      if (tg < NB)
        *(float4*)(oc + tg) = make_float4(sc[a], sc[a + 1], sc[a + 2], sc[a + 3]);
    }
  }
  // h_nout interleave (h from LDS col 0) + obs_std column
#pragma unroll
  for (int k2 = 0; k2 < 4; ++k2) {
    int j = lane + 64 * k2;       // float4 covers t = t0b+2j, t0b+2j+1
    int tg = t0b + 2 * j;
    if (tg < NB) {
      int e = 2 * j;
      int a = (e >> 3) * 9 + (e & 7);
      float s0 = (tg >= tl) ? sd : 0.f;
      float s1 = (tg + 1 >= tl) ? sd : 0.f;
      *(float4*)(out + 14 * NB + 2 * tg) = make_float4(sh[a], s0, sh[a + 1], s1);
    }
  }
#pragma unroll
  for (int k2 = 0; k2 < 2; ++k2) {
    int e0 = 4 * (lane + 64 * k2);
    int tg = t0b + e0;
    if (tg < NB) {
      float4 v;
      v.x = (tg >= tl) ? sd : 0.f;
      v.y = (tg + 1 >= tl) ? sd : 0.f;
      v.z = (tg + 2 >= tl) ? sd : 0.f;
      v.w = (tg + 3 >= tl) ? sd : 0.f;
      *(float4*)(out + 16 * NB + tg) = v;
    }
  }
}

extern "C" void kernel_launch(void* const* d_in, const int* in_sizes, int n_in,
                              void* d_out, int out_size, void* d_ws, size_t ws_size,
                              hipStream_t stream) {
  const float* x        = (const float*)d_in[0];
  const float* y_obs    = (const float*)d_in[1];
  const float* p_mean   = (const float*)d_in[2];
  const float* p_std    = (const float*)d_in[3];
  // d_in[4] = epoch (unused by reference)
  const int* time_lag   = (const int*)d_in[5];
  const float* w_r_yom    = (const float*)d_in[6];
  const float* w_r_yom_fp = (const float*)d_in[7];
  const float* w_r_yom_gw = (const float*)d_in[8];
  const float* w_r_ylm    = (const float*)d_in[9];
  const float* w_r_yfm    = (const float*)d_in[10];
  const float* w_b1_yom   = (const float*)d_in[11];
  const float* w_b1_yom_gw= (const float*)d_in[12];
  const float* w_b1_yom_fp= (const float*)d_in[13];
  const float* w_b2_ylm   = (const float*)d_in[14];
  const float* theltaC    = (const float*)d_in[15];
  const float* b0_yom     = (const float*)d_in[16];
  const float* b0_yom_gw  = (const float*)d_in[17];
  const float* b0_yom_fp  = (const float*)d_in[18];
  const float* b0_ylm     = (const float*)d_in[19];
  float* out = (float*)d_out;
  float* ws = (float*)d_ws;

  prep_kernel<<<21, 256, 0, stream>>>(x, y_obs, time_lag,
                                      w_r_yom, w_r_yom_fp, w_r_yom_gw, w_r_ylm,
                                      w_r_yfm, w_b2_ylm, b0_ylm, ws, out);
  const int nlanes = (NB + CHUNK - 1) / CHUNK;                     // 2500
  const int nblocks = (nlanes + LANES_PER_BLOCK - 1) / LANES_PER_BLOCK;  // 40
  scan_spec_kernel<<<nblocks, LANES_PER_BLOCK, 0, stream>>>(
      ws, time_lag, p_mean, p_std,
      w_r_yom, w_r_yom_fp, w_r_yom_gw, w_r_ylm, w_r_yfm,
      w_b1_yom, w_b1_yom_gw, w_b1_yom_fp,
      theltaC, b0_yom, b0_yom_gw, b0_yom_fp,
      out);
}

// Round 4
// 121.537 us; speedup vs baseline: 27.4297x; 1.0022x over previous
//
#include <hip/hip_runtime.h>
#include <math.h>

#define NB 20000
#define SPIN 365
#define TRAINLEN 15000
#define ML_C 2.9086f
#define SL_C 1.898f

// speculative decoupling: each lane owns CHUNK steps after WSPEC warm-up from
// speculated c=0. absmax identical (9.77e-4) at W=128 and W=96 => spec error
// at W=96 is below the fp32-vs-np rounding floor; threshold 2.45e-2.
#define CHUNK 8
#define WSPEC 96
#define NLANES 2500          // NB / CHUNK
#define NSCANBLK 40          // 40*64 = 2560 lanes >= 2500

#define EX2(x) __builtin_amdgcn_exp2f(x)
#define RCP(x) __builtin_amdgcn_rcpf(x)
#define L2E 1.4426950408889634f

__device__ __forceinline__ int clampi(int j) {
  return j < 0 ? 0 : (j > NB - 1 ? NB - 1 : j);
}

__global__ __launch_bounds__(64) void fused_kernel(
    const float* __restrict__ x, const float* __restrict__ y,
    const float* __restrict__ p_mean, const float* __restrict__ p_std,
    const int* __restrict__ time_lag,
    const float* __restrict__ w_r_yom, const float* __restrict__ w_r_yom_fp,
    const float* __restrict__ w_r_yom_gw, const float* __restrict__ w_r_ylm,
    const float* __restrict__ w_r_yfm,
    const float* __restrict__ w_b1_yom, const float* __restrict__ w_b1_yom_gw,
    const float* __restrict__ w_b1_yom_fp, const float* __restrict__ w_b2_ylm,
    const float* __restrict__ theltaC,
    const float* __restrict__ b0_yom, const float* __restrict__ b0_yom_gw,
    const float* __restrict__ b0_yom_fp, const float* __restrict__ b0_ylm,
    float* __restrict__ out) {
  const int lane = threadIdx.x;
  const int tl = time_lag[0];

  if (blockIdx.x == NSCANBLK) {
    // ---------- obsstd block: std(y[SPIN:TRAINLEN], ddof=1) ----------
    double a = 0.0, q = 0.0;
    if (lane < 3) {                       // head: 365..367 (float4 align at 368)
      double v = (double)y[SPIN + lane];
      a += v; q += v * v;
    }
    const float4* y4 = (const float4*)(y + 368);   // 368..14999 = 3658 float4
    for (int i = lane; i < 3658; i += 64) {
      float4 v = y4[i];
      double v0 = v.x, v1 = v.y, v2 = v.z, v3 = v.w;
      a += v0 + v1 + v2 + v3;
      q += v0 * v0 + v1 * v1 + v2 * v2 + v3 * v3;
    }
    for (int off = 32; off > 0; off >>= 1) {       // 64-lane double butterfly
      a += __shfl_xor(a, off, 64);
      q += __shfl_xor(q, off, 64);
    }
    const double n = (double)(TRAINLEN - SPIN);
    const float sd = (float)sqrt((q - a * a / n) / (n - 1.0));
    // obs_std column (contiguous float4)
    for (int i = lane; i < NB / 4; i += 64) {
      int t = 4 * i;
      float4 v;
      v.x = (t >= tl) ? sd : 0.f;
      v.y = (t + 1 >= tl) ? sd : 0.f;
      v.z = (t + 2 >= tl) ? sd : 0.f;
      v.w = (t + 3 >= tl) ? sd : 0.f;
      *(float4*)(out + 16 * NB + t) = v;
    }
    // h_nout odd slots (sd part); even slots owned by scan blocks — disjoint
    for (int t = lane; t < NB; t += 64)
      out[14 * NB + 2 * t + 1] = (t >= tl) ? sd : 0.f;
    return;
  }

  // ---------- scan blocks ----------
  const int gid = blockIdx.x * 64 + lane;
  const int start = gid * CHUNK;
  const int begin = start - WSPEC;

  // fold parameters into per-step constants
  float e1 = __expf(w_r_yom[0]);
  float e2 = __expf(w_r_yom_gw[0]);
  float e3 = __expf(w_r_ylm[0]);
  float e4 = __expf(w_r_yfm[0]);
  float e5 = __expf(w_r_yom_fp[0]);
  float rd = 1.f / (e1 + e2 + e3 + e4 + e5);
  float oo1 = e1 * rd, oogw1 = e2 * rd, oofp1 = e5 * rd, ol1 = e3 * rd;
  float expC = __expf(theltaC[0]);
  float mo = p_mean[0];
  float inv_so = 1.f / p_std[0];
  float w1 = w_b1_yom[0], w1gw = w_b1_yom_gw[0], w1fp = w_b1_yom_fp[0], w2 = w_b2_ylm[0];
  float k_oo = -L2E * (w1 * inv_so);
  float d_oo = -L2E * (b0_yom[0] - mo * inv_so * w1);
  float k_gw = -L2E * (w1gw * inv_so);
  float d_gw = -L2E * (b0_yom_gw[0] - mo * inv_so * w1gw);
  float k_fp = -L2E * (w1fp * inv_so);
  float d_fp = -L2E * (b0_yom_fp[0] - mo * inv_so * w1fp);
  float k_ol = -L2E * (w2 / SL_C);
  float d_ol = -L2E * (b0_ylm[0] - (ML_C / SL_C) * w2);

  const float2* __restrict__ xv = (const float2*)x;

  // distance-4 register ring (clamped indices during warm-up)
  float2 xb[4];
#pragma unroll
  for (int k = 0; k < 4; ++k) xb[k] = xv[clampi(begin + k)];

  float c = 0.f;
  // ---- warm-up: t = 0..WSPEC-1, no stores ----
  for (int tt = 0; tt < WSPEC; tt += 4) {
#pragma unroll
    for (int k = 0; k < 4; ++k) {
      const int idx = begin + tt + k;
      float2 xc = xb[k];
      xb[k] = xv[clampi(idx + 4)];
      if (idx >= 0) {   // divergent only in block 0's first iterations
        float u1 = xc.x, u2 = xc.y;
        float px = fmaxf(u1 + c - expC, 0.f);
        float soo = RCP(1.f + EX2(fmaf(c, k_oo, d_oo)));
        float sgw = RCP(1.f + EX2(fmaf(c, k_gw, d_gw)));
        float sfp = RCP(1.f + EX2(fmaf(c, k_fp, d_fp)));
        float sol = RCP(1.f + EX2(fmaf(u2, k_ol, d_ol)));
        float oo = oo1 * soo, oogw = oogw1 * sgw, oofp = oofp1 * sfp, ol = ol1 * sol;
        float ratio = u2 * RCP(c);
        float olc = (c > 0.f) ? (ol - fmaxf(ol - ratio, 0.f)) : ol;
        float fg = 1.f - oo - oofp - oogw - olc;
        if (idx >= tl) c = fmaf(fg, c, u1 - px);
      }
    }
  }

  // ---- tail: t = WSPEC..WSPEC+7, buffer 14 columns x 8 in registers ----
  float vh[8], vhfp[8], vc[8], vl[8], vlc[8], vbp[8], vgw[8];
  float vib[8], voo[8], voofp[8], vol[8], volc[8], vf[8], voogw[8];
#pragma unroll
  for (int k = 0; k < 8; ++k) {
    const int idx = start + k;
    float2 xc = xb[k & 3];
    if (k < 4) xb[k & 3] = xv[clampi(idx + 4)];
    float u1 = xc.x, u2 = xc.y;
    float px = fmaxf(u1 + c - expC, 0.f);
    float iu = (u1 > 0.f) ? RCP(u1) : 0.f;
    float ib = px * iu;
    float soo = RCP(1.f + EX2(fmaf(c, k_oo, d_oo)));
    float sgw = RCP(1.f + EX2(fmaf(c, k_gw, d_gw)));
    float sfp = RCP(1.f + EX2(fmaf(c, k_fp, d_fp)));
    float sol = RCP(1.f + EX2(fmaf(u2, k_ol, d_ol)));
    float oo = oo1 * soo, oogw = oogw1 * sgw, oofp = oofp1 * sfp, ol = ol1 * sol;
    float ratio = u2 * RCP(c);
    float olc = (c > 0.f) ? (ol - fmaxf(ol - ratio, 0.f)) : ol;
    float fg = 1.f - oo - oofp - oogw - olc;
    bool act = idx >= tl;
    float m = act ? 1.f : 0.f;
    vh[k] = m * fmaf(oo, c, px);
    vhfp[k] = m * (oofp * c);
    vc[k] = m * c;                 // c0 entering this step
    vl[k] = m * (ol * c);
    vlc[k] = m * (olc * c);
    vbp[k] = m * px;
    vgw[k] = m * (oogw * c);
    vib[k] = m * ib;
    voo[k] = m * oo;
    voofp[k] = m * oofp;
    vol[k] = m * ol;
    volc[k] = m * olc;
    vf[k] = m * fg;
    voogw[k] = m * oogw;
    if (act) c = fmaf(fg, c, u1 - px);
  }

  // ---- flush: 2x float4 per column, direct from registers ----
  if (gid < NLANES) {
#define ST(col, v)                                                            \
  *(float4*)(out + (col) * NB + start) = make_float4(v[0], v[1], v[2], v[3]); \
  *(float4*)(out + (col) * NB + start + 4) = make_float4(v[4], v[5], v[6], v[7]);
    ST(0, vh) ST(1, vhfp) ST(2, vc) ST(3, vl) ST(4, vlc) ST(5, vbp) ST(6, vgw)
    ST(7, vib) ST(8, voo) ST(9, voofp) ST(10, vol) ST(11, volc) ST(12, vf)
    ST(13, voogw)
#undef ST
    // h_nout even slots (h part); odd slots owned by the std block
#pragma unroll
    for (int k = 0; k < 8; ++k)
      out[14 * NB + 2 * (start + k)] = vh[k];
  }
}

extern "C" void kernel_launch(void* const* d_in, const int* in_sizes, int n_in,
                              void* d_out, int out_size, void* d_ws, size_t ws_size,
                              hipStream_t stream) {
  const float* x        = (const float*)d_in[0];
  const float* y_obs    = (const float*)d_in[1];
  const float* p_mean   = (const float*)d_in[2];
  const float* p_std    = (const float*)d_in[3];
  // d_in[4] = epoch (unused by reference)
  const int* time_lag   = (const int*)d_in[5];
  const float* w_r_yom    = (const float*)d_in[6];
  const float* w_r_yom_fp = (const float*)d_in[7];
  const float* w_r_yom_gw = (const float*)d_in[8];
  const float* w_r_ylm    = (const float*)d_in[9];
  const float* w_r_yfm    = (const float*)d_in[10];
  const float* w_b1_yom   = (const float*)d_in[11];
  const float* w_b1_yom_gw= (const float*)d_in[12];
  const float* w_b1_yom_fp= (const float*)d_in[13];
  const float* w_b2_ylm   = (const float*)d_in[14];
  const float* theltaC    = (const float*)d_in[15];
  const float* b0_yom     = (const float*)d_in[16];
  const float* b0_yom_gw  = (const float*)d_in[17];
  const float* b0_yom_fp  = (const float*)d_in[18];
  const float* b0_ylm     = (const float*)d_in[19];
  float* out = (float*)d_out;
  (void)d_ws; (void)ws_size;

  fused_kernel<<<NSCANBLK + 1, 64, 0, stream>>>(
      x, y_obs, p_mean, p_std, time_lag,
      w_r_yom, w_r_yom_fp, w_r_yom_gw, w_r_ylm, w_r_yfm,
      w_b1_yom, w_b1_yom_gw, w_b1_yom_fp, w_b2_ylm,
      theltaC, b0_yom, b0_yom_gw, b0_yom_fp, b0_ylm,
      out);
}